// Round 6
// baseline (425.060 us; speedup 1.0000x reference)
//
#include <hip/hip_runtime.h>
#include <math.h>

#define DIM 1024
#define ROWS 16384
#define SEQ 4096
#define MARGIN 0.012f
#define MAXC 24

typedef __bf16 v8bf __attribute__((ext_vector_type(8)));
typedef float v4f __attribute__((ext_vector_type(4)));

__device__ __forceinline__ unsigned short f2bf(float f){
  unsigned u = __float_as_uint(f);
  u = u + 0x7FFFu + ((u >> 16) & 1u);   // RNE
  return (unsigned short)(u >> 16);
}
__device__ __forceinline__ float bf2f(unsigned short h){
  return __uint_as_float(((unsigned)h) << 16);
}
__device__ __forceinline__ unsigned short relu_bf(unsigned short h){
  return (h & 0x8000u) ? (unsigned short)0 : h;
}
__device__ __forceinline__ void lds_fence(){
  __asm__ volatile("s_waitcnt lgkmcnt(0)" ::: "memory");
}

// ---- fused fp32->bf16 convert: y<16 -> x slab y; y>=16 -> weight slab y-16 ----
__global__ __launch_bounds__(256) void cvt_all(
    const float* __restrict__ x,
    const float* __restrict__ w0, const float* __restrict__ w1,
    const float* __restrict__ w2, const float* __restrict__ w3,
    const float* __restrict__ w4,
    unsigned short* __restrict__ xbf, unsigned short* __restrict__ wbf){
  const int y = blockIdx.y;
  const float* s;
  unsigned short* d;
  if (y < 16){ s = x + ((size_t)y << 20); d = xbf + ((size_t)y << 20); }
  else {
    const float* srcs[5] = {w0, w1, w2, w3, w4};
    s = srcs[y - 16]; d = wbf + ((size_t)(y - 16) << 20);
  }
  int i = (blockIdx.x * 256 + threadIdx.x) * 4;
  float4 f = *(const float4*)(s + i);
  ushort4 o;
  o.x = f2bf(f.x); o.y = f2bf(f.y); o.z = f2bf(f.z); o.w = f2bf(f.w);
  *(ushort4*)(d + i) = o;
}

// ------- bf16 GEMM: A(MxK) @ B(NtotxK)^T, outputs split per 1024 columns -------
// Block swizzle: n-block varies slowest so each XCD keeps one B-tile hot.
__global__ __launch_bounds__(256, 4) void gemm_bt(
    const unsigned short* __restrict__ A, const unsigned short* __restrict__ B,
    const float* __restrict__ bias0, const float* __restrict__ bias1,
    void* __restrict__ C0, void* __restrict__ C1, void* __restrict__ C2,
    int bf16mask)
{
  __shared__ unsigned short lA[128 * 32];
  __shared__ unsigned short lB[128 * 32];
  const int t = threadIdx.x;
  const int lane = t & 63, wave = t >> 6;
  const int bid = blockIdx.y * gridDim.x + blockIdx.x;   // gridDim.y == 128
  const int m0 = (bid & 127) * 128;
  const int n0 = (bid >> 7) * 128;
  const int wm = (wave >> 1) * 64, wn = (wave & 1) * 64;
  const int ar = lane & 15, aq = lane >> 4;

  v4f acc[4][4];
#pragma unroll
  for (int i = 0; i < 4; i++)
#pragma unroll
    for (int j = 0; j < 4; j++) acc[i][j] = v4f{0.f, 0.f, 0.f, 0.f};

  for (int k0 = 0; k0 < DIM; k0 += 32){
#pragma unroll
    for (int i = 0; i < 2; i++){
      int c = (wave * 2 + i) * 64 + lane;        // 512 16B chunks per tile
      int row = c >> 2, kq = c & 3;
      __builtin_amdgcn_global_load_lds(
        (const __attribute__((address_space(1))) void*)(A + (size_t)(m0 + row) * DIM + k0 + kq * 8),
        (__attribute__((address_space(3))) void*)(&lA[c * 8]), 16, 0, 0);
      __builtin_amdgcn_global_load_lds(
        (const __attribute__((address_space(1))) void*)(B + (size_t)(n0 + row) * DIM + k0 + kq * 8),
        (__attribute__((address_space(3))) void*)(&lB[c * 8]), 16, 0, 0);
    }
    __syncthreads();
    v8bf af[4], bf[4];
#pragma unroll
    for (int i = 0; i < 4; i++){
      af[i] = *(const v8bf*)&lA[(wm + i * 16 + ar) * 32 + aq * 8];
      bf[i] = *(const v8bf*)&lB[(wn + i * 16 + ar) * 32 + aq * 8];
    }
#pragma unroll
    for (int mi = 0; mi < 4; mi++)
#pragma unroll
      for (int ni = 0; ni < 4; ni++)
        acc[mi][ni] = __builtin_amdgcn_mfma_f32_16x16x32_bf16(af[mi], bf[ni], acc[mi][ni], 0, 0, 0);
    __syncthreads();
  }

  const int os = n0 >> 10;                       // 1024-aligned segment, block-uniform
  void* Cp = (os == 0) ? C0 : ((os == 1) ? C1 : C2);
  const float* bp = (os == 0) ? bias0 : ((os == 1) ? bias1 : nullptr);
  const bool half_out = ((bf16mask >> os) & 1) != 0;
#pragma unroll
  for (int mi = 0; mi < 4; mi++)
#pragma unroll
    for (int ni = 0; ni < 4; ni++){
      int col = (n0 + wn + ni * 16 + ar) & (DIM - 1);
      float bv = bp ? bp[col] : 0.f;
#pragma unroll
      for (int rr = 0; rr < 4; rr++){
        int rowg = m0 + wm + mi * 16 + aq * 4 + rr;
        float val = acc[mi][ni][rr] + bv;
        if (half_out) ((unsigned short*)Cp)[(size_t)rowg * DIM + col] = f2bf(val);
        else          ((float*)Cp)[(size_t)rowg * DIM + col] = val;
      }
    }
}

// ---- top-64 select: one row per WAVE, zero __syncthreads, bisection threshold ----
// gate_pre now bf16; margin widened to cover storage + GEMM quantization tails.
__global__ __launch_bounds__(256) void select_k(
  const unsigned short* __restrict__ gate_pre, const unsigned short* __restrict__ mag_pre,
  const float* __restrict__ x, const float* __restrict__ gW, const float* __restrict__ gb,
  unsigned short* __restrict__ xg)
{
  __shared__ int   s_cnt[4];
  __shared__ int   s_idx[4][MAXC];
  __shared__ float s_ex [4][MAXC];
  __shared__ int   s_res[4][MAXC];

  const int t = threadIdx.x;
  const int lane = t & 63, wave = t >> 6;
  const int r = blockIdx.x * 4 + wave;
  const size_t rb = (size_t)r * DIM;

  // load row into registers (coalesced ushort4/float4)
  float vg[16], vx[16];
  unsigned short mg[16];
#pragma unroll
  for (int c = 0; c < 4; c++){
    ushort4 g4 = *(const ushort4*)(gate_pre + rb + c * 256 + lane * 4);
    float4 x4 = *(const float4*)(x          + rb + c * 256 + lane * 4);
    ushort4 m4 = *(const ushort4*)(mag_pre  + rb + c * 256 + lane * 4);
    vg[c*4+0]=bf2f(g4.x); vg[c*4+1]=bf2f(g4.y); vg[c*4+2]=bf2f(g4.z); vg[c*4+3]=bf2f(g4.w);
    vx[c*4+0]=x4.x; vx[c*4+1]=x4.y; vx[c*4+2]=x4.z; vx[c*4+3]=x4.w;
    mg[c*4+0]=m4.x; mg[c*4+1]=m4.y; mg[c*4+2]=m4.z; mg[c*4+3]=m4.w;
  }
  if (lane == 0) s_cnt[wave] = 0;

  // bisection: bracket 64th-largest; invariant c(lo)>=64>c(hi), c(T)=#{v>T}
  float lo = -8.f, hi = 8.f;
#pragma unroll
  for (int it = 0; it < 15; it++){
    float mid = 0.5f * (lo + hi);
    int cn = 0;
#pragma unroll
    for (int e = 0; e < 16; e++) cn += (vg[e] > mid) ? 1 : 0;
#pragma unroll
    for (int m = 32; m; m >>= 1) cn += __shfl_xor(cn, m);
    if (cn >= 64) lo = mid; else hi = mid;
  }
  const float cl = lo - MARGIN, ch = hi + MARGIN;

  // count certain winners (v > ch)
  int n1 = 0;
#pragma unroll
  for (int e = 0; e < 16; e++) n1 += (vg[e] > ch) ? 1 : 0;
#pragma unroll
  for (int m = 32; m; m >>= 1) n1 += __shfl_xor(n1, m);
  const int s = 64 - n1;

  // collect ambiguous candidates (cl <= v <= ch) into per-wave LDS list
  lds_fence();
#pragma unroll
  for (int e = 0; e < 16; e++){
    float vv = vg[e];
    if (vv >= cl && vv <= ch){
      int p = atomicAdd(&s_cnt[wave], 1);
      if (p < MAXC) s_idx[wave][p] = (e >> 2) * 256 + lane * 4 + (e & 3);
    }
  }
  lds_fence();
  int namb = s_cnt[wave]; if (namb > MAXC) namb = MAXC;

  // fp32-exact recompute for each candidate (whole wave, x in registers)
  for (int i = 0; i < namb; i++){
    int d = s_idx[wave][i];
    const float* wr = gW + (size_t)d * DIM;
    float p = 0.f;
#pragma unroll
    for (int c = 0; c < 4; c++){
      float4 w4 = *(const float4*)(wr + c * 256 + lane * 4);
      p = fmaf(vx[c*4+0], w4.x, p); p = fmaf(vx[c*4+1], w4.y, p);
      p = fmaf(vx[c*4+2], w4.z, p); p = fmaf(vx[c*4+3], w4.w, p);
    }
#pragma unroll
    for (int m = 32; m; m >>= 1) p += __shfl_xor(p, m);
    if (lane == 0) s_ex[wave][i] = p + gb[d];
  }
  lds_fence();

  // rank candidates (tie-break lower index); mark winners with positive gate
  if (lane < namb){
    float e = s_ex[wave][lane]; int d = s_idx[wave][lane];
    int rank = 0;
    for (int j = 0; j < namb; j++){
      float ej = s_ex[wave][j]; int dj = s_idx[wave][j];
      if (ej > e || (ej == e && dj < d)) rank++;
    }
    s_res[wave][lane] = (rank < s && e > 0.f) ? 1 : 0;
  }
  lds_fence();

  // assemble output: certain winners from registers, candidate overrides from LDS
  unsigned short o16[16];
#pragma unroll
  for (int e = 0; e < 16; e++)
    o16[e] = (vg[e] > ch) ? ((vg[e] > 0.f) ? relu_bf(mg[e]) : (unsigned short)0)
                          : (unsigned short)0;
  for (int i = 0; i < namb; i++){
    int d = s_idx[wave][i];
    int res = s_res[wave][i];
    if (((d >> 2) & 63) == lane){
      int e = (d >> 8) * 4 + (d & 3);
      o16[e] = res ? relu_bf(mg[e]) : (unsigned short)0;
    }
  }
#pragma unroll
  for (int c = 0; c < 4; c++){
    ushort4 o; o.x = o16[c*4+0]; o.y = o16[c*4+1]; o.z = o16[c*4+2]; o.w = o16[c*4+3];
    *(ushort4*)(xg + rb + c * 256 + lane * 4) = o;
  }
}

// ------- epilogue: 4 rows/block, prev row + inverse-norms carried in registers -------
__global__ __launch_bounds__(256) void epilogue_k(
  const unsigned short* __restrict__ q_pre, const unsigned short* __restrict__ k_pre,
  const unsigned short* __restrict__ p_pre, float* __restrict__ out)
{
  const int r0 = blockIdx.x * 4;
  const int t = threadIdx.x;
  const int lane = t & 63, wave = t >> 6;
  __shared__ float red[16];

  const int rp = (r0 == 0) ? 0 : r0 - 1;
  float vqp[4], vkp[4], vpp[4];
  {
    ushort4 uq = *(const ushort4*)(q_pre + (size_t)rp * DIM + 4*t);
    ushort4 uk = *(const ushort4*)(k_pre + (size_t)rp * DIM + 4*t);
    ushort4 up = *(const ushort4*)(p_pre + (size_t)rp * DIM + 4*t);
    vqp[0]=bf2f(uq.x); vqp[1]=bf2f(uq.y); vqp[2]=bf2f(uq.z); vqp[3]=bf2f(uq.w);
    vkp[0]=bf2f(uk.x); vkp[1]=bf2f(uk.y); vkp[2]=bf2f(uk.z); vkp[3]=bf2f(uk.w);
    vpp[0]=bf2f(up.x); vpp[1]=bf2f(up.y); vpp[2]=bf2f(up.z); vpp[3]=bf2f(up.w);
  }
  float aq = 0.f, ak = 0.f;
#pragma unroll
  for (int j = 0; j < 4; j++){ aq = fmaf(vqp[j], vqp[j], aq); ak = fmaf(vkp[j], vkp[j], ak); }
#pragma unroll
  for (int m = 32; m; m >>= 1){ aq += __shfl_xor(aq, m); ak += __shfl_xor(ak, m); }
  if (lane == 0){ red[wave] = aq; red[4 + wave] = ak; }
  __syncthreads();
  float rqp = 1.f / fmaxf(sqrtf(red[0] + red[1] + red[2] + red[3]), 1e-12f);
  float rkp = 1.f / fmaxf(sqrtf(red[4] + red[5] + red[6] + red[7]), 1e-12f);
  __syncthreads();

  for (int rr = 0; rr < 4; rr++){
    const int r = r0 + rr;
    float vqc[4], vkc[4], vpc[4];
    {
      ushort4 uq = *(const ushort4*)(q_pre + (size_t)r * DIM + 4*t);
      ushort4 uk = *(const ushort4*)(k_pre + (size_t)r * DIM + 4*t);
      ushort4 up = *(const ushort4*)(p_pre + (size_t)r * DIM + 4*t);
      vqc[0]=bf2f(uq.x); vqc[1]=bf2f(uq.y); vqc[2]=bf2f(uq.z); vqc[3]=bf2f(uq.w);
      vkc[0]=bf2f(uk.x); vkc[1]=bf2f(uk.y); vkc[2]=bf2f(uk.z); vkc[3]=bf2f(uk.w);
      vpc[0]=bf2f(up.x); vpc[1]=bf2f(up.y); vpc[2]=bf2f(up.z); vpc[3]=bf2f(up.w);
    }
    const bool seg = (r & (SEQ - 1)) == 0;
    float aqc = 0.f, akc = 0.f;
#pragma unroll
    for (int j = 0; j < 4; j++){ aqc = fmaf(vqc[j], vqc[j], aqc); akc = fmaf(vkc[j], vkc[j], akc); }
    float dsum = 0.f;
    if (!seg){
#pragma unroll
      for (int j = 0; j < 2; j++){
        float ax = vpp[2*j], ay = vpp[2*j+1], bx = vpc[2*j], by = vpc[2*j+1];
        float ia = 1.f / fmaxf(sqrtf(ax * ax + ay * ay), 1e-12f);
        float ib = 1.f / fmaxf(sqrtf(bx * bx + by * by), 1e-12f);
        ax *= ia; ay *= ia; bx *= ib; by *= ib;
        float cross = ax * by - ay * bx;
        float dot = fminf(fmaxf(ax * bx + ay * by, -1.f), 1.f);
        dsum += fabsf(atan2f(cross, dot)) * 0.3183098861837907f;
      }
    }
#pragma unroll
    for (int m = 32; m; m >>= 1){
      aqc += __shfl_xor(aqc, m); akc += __shfl_xor(akc, m); dsum += __shfl_xor(dsum, m);
    }
    if (lane == 0){ red[wave] = aqc; red[4 + wave] = akc; red[8 + wave] = dsum; }
    __syncthreads();
    float rqc = 1.f / fmaxf(sqrtf(red[0] + red[1] + red[2] + red[3]), 1e-12f);
    float rkc = 1.f / fmaxf(sqrtf(red[4] + red[5] + red[6] + red[7]), 1e-12f);
    if (!seg){
      float tw = 0.f;
#pragma unroll
      for (int j = 0; j < 4; j++){
        float m = (vqc[j] * rqc) * (vkp[j] * rkp) - (vqp[j] * rqp) * (vkc[j] * rkc);
        tw = fmaf(m, m, tw);
      }
#pragma unroll
      for (int m = 32; m; m >>= 1) tw += __shfl_xor(tw, m);
      if (lane == 0) red[12 + wave] = tw;
      __syncthreads();
      if (t == 0){
        float dtot = red[8] + red[9] + red[10] + red[11];
        float twt = red[12] + red[13] + red[14] + red[15];
        out[r] = 0.5f * tanhf(sqrtf(twt)) + 0.5f * (dtot * (1.f / 512.f));
      }
    } else {
      if (t == 0) out[r] = 0.f;
    }
    __syncthreads();
#pragma unroll
    for (int j = 0; j < 4; j++){ vqp[j] = vqc[j]; vkp[j] = vkc[j]; vpp[j] = vpc[j]; }
    rqp = rqc; rkp = rkc;
  }
}

extern "C" void kernel_launch(void* const* d_in, const int* in_sizes, int n_in,
                              void* d_out, int out_size, void* d_ws, size_t ws_size,
                              hipStream_t stream)
{
  const float* x       = (const float*)d_in[0];
  const float* gate_W  = (const float*)d_in[1];
  const float* gate_b  = (const float*)d_in[2];
  const float* mag_W   = (const float*)d_in[3];
  const float* mag_b   = (const float*)d_in[4];
  const float* Wq      = (const float*)d_in[5];
  const float* Wk      = (const float*)d_in[6];
  const float* phase_W = (const float*)d_in[7];
  float* out = (float*)d_out;

  char* ws = (char*)d_ws;
  unsigned short* xbf = (unsigned short*)ws;                  // 32 MB @0 (reused as xg)
  unsigned short* wbf = (unsigned short*)(ws + 33554432);     // 10 MB @32M: [gate;mag;q;k;phase]
  unsigned short* gate_pre = (unsigned short*)(ws + 46137344);  // 32 MB @44M (reused as q_pre)
  unsigned short* mag_pre  = (unsigned short*)(ws + 79691776);  // 32 MB @76M (reused as k_pre)
  unsigned short* p_pre    = (unsigned short*)(ws + 113246208); // 32 MB @108M
  unsigned short* q_pre = gate_pre;
  unsigned short* k_pre = mag_pre;

  dim3 b256(256);
  cvt_all<<<dim3(1024, 21), b256, 0, stream>>>(x, gate_W, mag_W, Wq, Wk, phase_W, xbf, wbf);

  // gate+mag fused GEMM (N=2048): both segments bf16 out
  gemm_bt<<<dim3(16, 128), b256, 0, stream>>>(xbf, wbf, gate_b, mag_b,
                                              gate_pre, mag_pre, nullptr, 0b011);

  unsigned short* xg = xbf;   // xbf no longer needed
  select_k<<<ROWS / 4, b256, 0, stream>>>(gate_pre, mag_pre, x, gate_W, gate_b, xg);

  // q+k+phase fused GEMM (N=3072), all bf16 out
  gemm_bt<<<dim3(24, 128), b256, 0, stream>>>(xg, wbf + (2u << 20), nullptr, nullptr,
                                              q_pre, k_pre, p_pre, 0b111);

  epilogue_k<<<ROWS / 4, b256, 0, stream>>>(q_pre, k_pre, p_pre, out);
}

// Round 7
// 392.682 us; speedup vs baseline: 1.0825x; 1.0825x over previous
//
#include <hip/hip_runtime.h>
#include <math.h>

#define DIM 1024
#define ROWS 16384
#define SEQ 4096
#define MARGIN 0.012f
#define MAXC 24

typedef __bf16 v8bf __attribute__((ext_vector_type(8)));
typedef float v4f __attribute__((ext_vector_type(4)));
typedef int v8i __attribute__((ext_vector_type(8)));

__device__ __forceinline__ unsigned short f2bf(float f){
  unsigned u = __float_as_uint(f);
  u = u + 0x7FFFu + ((u >> 16) & 1u);   // RNE
  return (unsigned short)(u >> 16);
}
__device__ __forceinline__ float bf2f(unsigned short h){
  return __uint_as_float(((unsigned)h) << 16);
}
__device__ __forceinline__ unsigned short relu_bf(unsigned short h){
  return (h & 0x8000u) ? (unsigned short)0 : h;
}
// SW float -> OCP e4m3fn (RNE, saturating) — avoids cvt-builtin availability risk
__device__ __forceinline__ unsigned f2fp8(float f){
  float a = fabsf(f);
  unsigned sign = (__float_as_uint(f) >> 24) & 0x80u;
  if (a >= 448.f) return sign | 0x7Eu;
  if (a < 0.015625f){                       // subnormal, step 2^-9
    int k = (int)rintf(a * 512.f);          // RNE
    if (k >= 8) return sign | 0x08u;
    return sign | (unsigned)k;
  }
  unsigned u = __float_as_uint(a);
  u += 0x7FFFFu + ((u >> 20) & 1u);         // RNE at 3 mantissa bits
  int e = (int)((u >> 23) & 0xFFu) - 127;
  unsigned m = (u >> 20) & 7u;
  if (e > 8) return sign | 0x7Eu;
  return sign | ((unsigned)(e + 7) << 3) | m;
}
__device__ __forceinline__ void lds_fence(){
  __asm__ volatile("s_waitcnt lgkmcnt(0)" ::: "memory");
}

// ---- fused convert: y<16 x->bf16; y=16,17 gate/mag W->bf16; y=18..20 q/k/p W->fp8(x32) ----
__global__ __launch_bounds__(256) void cvt_all(
    const float* __restrict__ x,
    const float* __restrict__ w0, const float* __restrict__ w1,
    const float* __restrict__ w2, const float* __restrict__ w3,
    const float* __restrict__ w4,
    unsigned short* __restrict__ xbf, unsigned short* __restrict__ wbf,
    unsigned char* __restrict__ wf8){
  const int y = blockIdx.y;
  int i = (blockIdx.x * 256 + threadIdx.x) * 4;
  if (y < 16){
    const float* s = x + ((size_t)y << 20);
    float4 f = *(const float4*)(s + i);
    ushort4 o; o.x = f2bf(f.x); o.y = f2bf(f.y); o.z = f2bf(f.z); o.w = f2bf(f.w);
    *(ushort4*)(xbf + ((size_t)y << 20) + i) = o;
  } else if (y < 18){
    const float* s = (y == 16) ? w0 : w1;
    float4 f = *(const float4*)(s + i);
    ushort4 o; o.x = f2bf(f.x); o.y = f2bf(f.y); o.z = f2bf(f.z); o.w = f2bf(f.w);
    *(ushort4*)(wbf + ((size_t)(y - 16) << 20) + i) = o;
  } else {
    const float* s = (y == 18) ? w2 : ((y == 19) ? w3 : w4);
    float4 f = *(const float4*)(s + i);
    unsigned u = f2fp8(f.x * 32.f) | (f2fp8(f.y * 32.f) << 8) |
                 (f2fp8(f.z * 32.f) << 16) | (f2fp8(f.w * 32.f) << 24);
    *(unsigned*)(wf8 + ((size_t)(y - 18) << 20) + i) = u;
  }
}

// ------- bf16 GEMM (GEMM1): A(MxK) @ B(2048xK)^T -> gate/mag bf16 -------
__global__ __launch_bounds__(256, 4) void gemm_bt(
    const unsigned short* __restrict__ A, const unsigned short* __restrict__ B,
    const float* __restrict__ bias0, const float* __restrict__ bias1,
    void* __restrict__ C0, void* __restrict__ C1, void* __restrict__ C2,
    int bf16mask)
{
  __shared__ unsigned short lA[128 * 32];
  __shared__ unsigned short lB[128 * 32];
  const int t = threadIdx.x;
  const int lane = t & 63, wave = t >> 6;
  const int bid = blockIdx.y * gridDim.x + blockIdx.x;
  const int m0 = (bid & 127) * 128;
  const int n0 = (bid >> 7) * 128;
  const int wm = (wave >> 1) * 64, wn = (wave & 1) * 64;
  const int ar = lane & 15, aq = lane >> 4;

  v4f acc[4][4];
#pragma unroll
  for (int i = 0; i < 4; i++)
#pragma unroll
    for (int j = 0; j < 4; j++) acc[i][j] = v4f{0.f, 0.f, 0.f, 0.f};

  for (int k0 = 0; k0 < DIM; k0 += 32){
#pragma unroll
    for (int i = 0; i < 2; i++){
      int c = (wave * 2 + i) * 64 + lane;
      int row = c >> 2, kq = c & 3;
      __builtin_amdgcn_global_load_lds(
        (const __attribute__((address_space(1))) void*)(A + (size_t)(m0 + row) * DIM + k0 + kq * 8),
        (__attribute__((address_space(3))) void*)(&lA[c * 8]), 16, 0, 0);
      __builtin_amdgcn_global_load_lds(
        (const __attribute__((address_space(1))) void*)(B + (size_t)(n0 + row) * DIM + k0 + kq * 8),
        (__attribute__((address_space(3))) void*)(&lB[c * 8]), 16, 0, 0);
    }
    __syncthreads();
    v8bf af[4], bf[4];
#pragma unroll
    for (int i = 0; i < 4; i++){
      af[i] = *(const v8bf*)&lA[(wm + i * 16 + ar) * 32 + aq * 8];
      bf[i] = *(const v8bf*)&lB[(wn + i * 16 + ar) * 32 + aq * 8];
    }
#pragma unroll
    for (int mi = 0; mi < 4; mi++)
#pragma unroll
      for (int ni = 0; ni < 4; ni++)
        acc[mi][ni] = __builtin_amdgcn_mfma_f32_16x16x32_bf16(af[mi], bf[ni], acc[mi][ni], 0, 0, 0);
    __syncthreads();
  }

  const int os = n0 >> 10;
  void* Cp = (os == 0) ? C0 : ((os == 1) ? C1 : C2);
  const float* bp = (os == 0) ? bias0 : ((os == 1) ? bias1 : nullptr);
  const bool half_out = ((bf16mask >> os) & 1) != 0;
#pragma unroll
  for (int mi = 0; mi < 4; mi++)
#pragma unroll
    for (int ni = 0; ni < 4; ni++){
      int col = (n0 + wn + ni * 16 + ar) & (DIM - 1);
      float bv = bp ? bp[col] : 0.f;
#pragma unroll
      for (int rr = 0; rr < 4; rr++){
        int rowg = m0 + wm + mi * 16 + aq * 4 + rr;
        float val = acc[mi][ni][rr] + bv;
        if (half_out) ((unsigned short*)Cp)[(size_t)rowg * DIM + col] = f2bf(val);
        else          ((float*)Cp)[(size_t)rowg * DIM + col] = val;
      }
    }
}

// ------- MX-fp8 GEMM (GEMM2): xg8(Mx1024) @ Wf8(3072x1024)^T -> q/k/p bf16 * (1/32) -------
// 16x16x128 f8f6f4, unit scales (0x7F). A/B frags use identical (lane,reg)->k maps,
// so the exact intra-fragment k order cancels in the dot product.
__global__ __launch_bounds__(256, 3) void gemm8(
    const unsigned char* __restrict__ A, const unsigned char* __restrict__ B,
    unsigned short* __restrict__ C0, unsigned short* __restrict__ C1,
    unsigned short* __restrict__ C2)
{
  __shared__ unsigned char lA[128 * 128];
  __shared__ unsigned char lB[128 * 128];
  const int t = threadIdx.x;
  const int lane = t & 63, wave = t >> 6;
  const int bid = blockIdx.y * gridDim.x + blockIdx.x;
  const int m0 = (bid & 127) * 128;
  const int n0 = (bid >> 7) * 128;
  const int wm = (wave >> 1) * 64, wn = (wave & 1) * 64;
  const int ar = lane & 15, aq = lane >> 4;   // aq = k-quarter (32 elems each)

  v4f acc[4][4];
#pragma unroll
  for (int i = 0; i < 4; i++)
#pragma unroll
    for (int j = 0; j < 4; j++) acc[i][j] = v4f{0.f, 0.f, 0.f, 0.f};

  for (int k0 = 0; k0 < DIM; k0 += 128){
#pragma unroll
    for (int i = 0; i < 4; i++){
      int c = (wave * 4 + i) * 64 + lane;      // 1024 chunks of 16B per tile
      int row = c >> 3, kq = c & 7;
      __builtin_amdgcn_global_load_lds(
        (const __attribute__((address_space(1))) void*)(A + (size_t)(m0 + row) * DIM + k0 + kq * 16),
        (__attribute__((address_space(3))) void*)(&lA[c * 16]), 16, 0, 0);
      __builtin_amdgcn_global_load_lds(
        (const __attribute__((address_space(1))) void*)(B + (size_t)(n0 + row) * DIM + k0 + kq * 16),
        (__attribute__((address_space(3))) void*)(&lB[c * 16]), 16, 0, 0);
    }
    __syncthreads();
    v8i a8[4], b8[4];
#pragma unroll
    for (int i = 0; i < 4; i++){
      a8[i] = *(const v8i*)&lA[(wm + i * 16 + ar) * 128 + aq * 32];
      b8[i] = *(const v8i*)&lB[(wn + i * 16 + ar) * 128 + aq * 32];
    }
#pragma unroll
    for (int mi = 0; mi < 4; mi++)
#pragma unroll
      for (int ni = 0; ni < 4; ni++)
        acc[mi][ni] = __builtin_amdgcn_mfma_scale_f32_16x16x128_f8f6f4(
            a8[mi], b8[ni], acc[mi][ni], 0, 0, 0, 127u, 0, 127u);
    __syncthreads();
  }

  const int os = n0 >> 10;
  unsigned short* Cp = (os == 0) ? C0 : ((os == 1) ? C1 : C2);
#pragma unroll
  for (int mi = 0; mi < 4; mi++)
#pragma unroll
    for (int ni = 0; ni < 4; ni++){
      int col = (n0 + wn + ni * 16 + ar) & (DIM - 1);
#pragma unroll
      for (int rr = 0; rr < 4; rr++){
        int rowg = m0 + wm + mi * 16 + aq * 4 + rr;
        Cp[(size_t)rowg * DIM + col] = f2bf(acc[mi][ni][rr] * 0.03125f);
      }
    }
}

// ---- top-64 select: one row per WAVE, bisection threshold + fp32-exact fixup; fp8 out ----
__global__ __launch_bounds__(256) void select_k(
  const unsigned short* __restrict__ gate_pre, const unsigned short* __restrict__ mag_pre,
  const float* __restrict__ x, const float* __restrict__ gW, const float* __restrict__ gb,
  unsigned char* __restrict__ xg8)
{
  __shared__ int   s_cnt[4];
  __shared__ int   s_idx[4][MAXC];
  __shared__ float s_ex [4][MAXC];
  __shared__ int   s_res[4][MAXC];

  const int t = threadIdx.x;
  const int lane = t & 63, wave = t >> 6;
  const int r = blockIdx.x * 4 + wave;
  const size_t rb = (size_t)r * DIM;

  float vg[16], vx[16];
  unsigned short mg[16];
#pragma unroll
  for (int c = 0; c < 4; c++){
    ushort4 g4 = *(const ushort4*)(gate_pre + rb + c * 256 + lane * 4);
    float4 x4 = *(const float4*)(x          + rb + c * 256 + lane * 4);
    ushort4 m4 = *(const ushort4*)(mag_pre  + rb + c * 256 + lane * 4);
    vg[c*4+0]=bf2f(g4.x); vg[c*4+1]=bf2f(g4.y); vg[c*4+2]=bf2f(g4.z); vg[c*4+3]=bf2f(g4.w);
    vx[c*4+0]=x4.x; vx[c*4+1]=x4.y; vx[c*4+2]=x4.z; vx[c*4+3]=x4.w;
    mg[c*4+0]=m4.x; mg[c*4+1]=m4.y; mg[c*4+2]=m4.z; mg[c*4+3]=m4.w;
  }
  if (lane == 0) s_cnt[wave] = 0;

  float lo = -8.f, hi = 8.f;
#pragma unroll
  for (int it = 0; it < 15; it++){
    float mid = 0.5f * (lo + hi);
    int cn = 0;
#pragma unroll
    for (int e = 0; e < 16; e++) cn += (vg[e] > mid) ? 1 : 0;
#pragma unroll
    for (int m = 32; m; m >>= 1) cn += __shfl_xor(cn, m);
    if (cn >= 64) lo = mid; else hi = mid;
  }
  const float cl = lo - MARGIN, ch = hi + MARGIN;

  int n1 = 0;
#pragma unroll
  for (int e = 0; e < 16; e++) n1 += (vg[e] > ch) ? 1 : 0;
#pragma unroll
  for (int m = 32; m; m >>= 1) n1 += __shfl_xor(n1, m);
  const int s = 64 - n1;

  lds_fence();
#pragma unroll
  for (int e = 0; e < 16; e++){
    float vv = vg[e];
    if (vv >= cl && vv <= ch){
      int p = atomicAdd(&s_cnt[wave], 1);
      if (p < MAXC) s_idx[wave][p] = (e >> 2) * 256 + lane * 4 + (e & 3);
    }
  }
  lds_fence();
  int namb = s_cnt[wave]; if (namb > MAXC) namb = MAXC;

  for (int i = 0; i < namb; i++){
    int d = s_idx[wave][i];
    const float* wr = gW + (size_t)d * DIM;
    float p = 0.f;
#pragma unroll
    for (int c = 0; c < 4; c++){
      float4 w4 = *(const float4*)(wr + c * 256 + lane * 4);
      p = fmaf(vx[c*4+0], w4.x, p); p = fmaf(vx[c*4+1], w4.y, p);
      p = fmaf(vx[c*4+2], w4.z, p); p = fmaf(vx[c*4+3], w4.w, p);
    }
#pragma unroll
    for (int m = 32; m; m >>= 1) p += __shfl_xor(p, m);
    if (lane == 0) s_ex[wave][i] = p + gb[d];
  }
  lds_fence();

  if (lane < namb){
    float e = s_ex[wave][lane]; int d = s_idx[wave][lane];
    int rank = 0;
    for (int j = 0; j < namb; j++){
      float ej = s_ex[wave][j]; int dj = s_idx[wave][j];
      if (ej > e || (ej == e && dj < d)) rank++;
    }
    s_res[wave][lane] = (rank < s && e > 0.f) ? 1 : 0;
  }
  lds_fence();

  float vals[16];
#pragma unroll
  for (int e = 0; e < 16; e++)
    vals[e] = (vg[e] > ch && vg[e] > 0.f) ? bf2f(relu_bf(mg[e])) : 0.f;
  for (int i = 0; i < namb; i++){
    int d = s_idx[wave][i];
    int res = s_res[wave][i];
    if (((d >> 2) & 63) == lane){
      int e = (d >> 8) * 4 + (d & 3);
      vals[e] = res ? bf2f(relu_bf(mg[e])) : 0.f;
    }
  }
#pragma unroll
  for (int c = 0; c < 4; c++){
    unsigned u = f2fp8(vals[c*4+0]) | (f2fp8(vals[c*4+1]) << 8) |
                 (f2fp8(vals[c*4+2]) << 16) | (f2fp8(vals[c*4+3]) << 24);
    *(unsigned*)(xg8 + rb + c * 256 + lane * 4) = u;
  }
}

// ------- epilogue: 4 rows/block, prev row + inverse-norms carried in registers -------
__global__ __launch_bounds__(256) void epilogue_k(
  const unsigned short* __restrict__ q_pre, const unsigned short* __restrict__ k_pre,
  const unsigned short* __restrict__ p_pre, float* __restrict__ out)
{
  const int r0 = blockIdx.x * 4;
  const int t = threadIdx.x;
  const int lane = t & 63, wave = t >> 6;
  __shared__ float red[16];

  const int rp = (r0 == 0) ? 0 : r0 - 1;
  float vqp[4], vkp[4], vpp[4];
  {
    ushort4 uq = *(const ushort4*)(q_pre + (size_t)rp * DIM + 4*t);
    ushort4 uk = *(const ushort4*)(k_pre + (size_t)rp * DIM + 4*t);
    ushort4 up = *(const ushort4*)(p_pre + (size_t)rp * DIM + 4*t);
    vqp[0]=bf2f(uq.x); vqp[1]=bf2f(uq.y); vqp[2]=bf2f(uq.z); vqp[3]=bf2f(uq.w);
    vkp[0]=bf2f(uk.x); vkp[1]=bf2f(uk.y); vkp[2]=bf2f(uk.z); vkp[3]=bf2f(uk.w);
    vpp[0]=bf2f(up.x); vpp[1]=bf2f(up.y); vpp[2]=bf2f(up.z); vpp[3]=bf2f(up.w);
  }
  float aq = 0.f, ak = 0.f;
#pragma unroll
  for (int j = 0; j < 4; j++){ aq = fmaf(vqp[j], vqp[j], aq); ak = fmaf(vkp[j], vkp[j], ak); }
#pragma unroll
  for (int m = 32; m; m >>= 1){ aq += __shfl_xor(aq, m); ak += __shfl_xor(ak, m); }
  if (lane == 0){ red[wave] = aq; red[4 + wave] = ak; }
  __syncthreads();
  float rqp = 1.f / fmaxf(sqrtf(red[0] + red[1] + red[2] + red[3]), 1e-12f);
  float rkp = 1.f / fmaxf(sqrtf(red[4] + red[5] + red[6] + red[7]), 1e-12f);
  __syncthreads();

  for (int rr = 0; rr < 4; rr++){
    const int r = r0 + rr;
    float vqc[4], vkc[4], vpc[4];
    {
      ushort4 uq = *(const ushort4*)(q_pre + (size_t)r * DIM + 4*t);
      ushort4 uk = *(const ushort4*)(k_pre + (size_t)r * DIM + 4*t);
      ushort4 up = *(const ushort4*)(p_pre + (size_t)r * DIM + 4*t);
      vqc[0]=bf2f(uq.x); vqc[1]=bf2f(uq.y); vqc[2]=bf2f(uq.z); vqc[3]=bf2f(uq.w);
      vkc[0]=bf2f(uk.x); vkc[1]=bf2f(uk.y); vkc[2]=bf2f(uk.z); vkc[3]=bf2f(uk.w);
      vpc[0]=bf2f(up.x); vpc[1]=bf2f(up.y); vpc[2]=bf2f(up.z); vpc[3]=bf2f(up.w);
    }
    const bool seg = (r & (SEQ - 1)) == 0;
    float aqc = 0.f, akc = 0.f;
#pragma unroll
    for (int j = 0; j < 4; j++){ aqc = fmaf(vqc[j], vqc[j], aqc); akc = fmaf(vkc[j], vkc[j], akc); }
    float dsum = 0.f;
    if (!seg){
#pragma unroll
      for (int j = 0; j < 2; j++){
        float ax = vpp[2*j], ay = vpp[2*j+1], bx = vpc[2*j], by = vpc[2*j+1];
        float ia = 1.f / fmaxf(sqrtf(ax * ax + ay * ay), 1e-12f);
        float ib = 1.f / fmaxf(sqrtf(bx * bx + by * by), 1e-12f);
        ax *= ia; ay *= ia; bx *= ib; by *= ib;
        float cross = ax * by - ay * bx;
        float dot = fminf(fmaxf(ax * bx + ay * by, -1.f), 1.f);
        dsum += fabsf(atan2f(cross, dot)) * 0.3183098861837907f;
      }
    }
#pragma unroll
    for (int m = 32; m; m >>= 1){
      aqc += __shfl_xor(aqc, m); akc += __shfl_xor(akc, m); dsum += __shfl_xor(dsum, m);
    }
    if (lane == 0){ red[wave] = aqc; red[4 + wave] = akc; red[8 + wave] = dsum; }
    __syncthreads();
    float rqc = 1.f / fmaxf(sqrtf(red[0] + red[1] + red[2] + red[3]), 1e-12f);
    float rkc = 1.f / fmaxf(sqrtf(red[4] + red[5] + red[6] + red[7]), 1e-12f);
    if (!seg){
      float tw = 0.f;
#pragma unroll
      for (int j = 0; j < 4; j++){
        float m = (vqc[j] * rqc) * (vkp[j] * rkp) - (vqp[j] * rqp) * (vkc[j] * rkc);
        tw = fmaf(m, m, tw);
      }
#pragma unroll
      for (int m = 32; m; m >>= 1) tw += __shfl_xor(tw, m);
      if (lane == 0) red[12 + wave] = tw;
      __syncthreads();
      if (t == 0){
        float dtot = red[8] + red[9] + red[10] + red[11];
        float twt = red[12] + red[13] + red[14] + red[15];
        out[r] = 0.5f * tanhf(sqrtf(twt)) + 0.5f * (dtot * (1.f / 512.f));
      }
    } else {
      if (t == 0) out[r] = 0.f;
    }
    __syncthreads();
#pragma unroll
    for (int j = 0; j < 4; j++){ vqp[j] = vqc[j]; vkp[j] = vkc[j]; vpp[j] = vpc[j]; }
    rqp = rqc; rkp = rkc;
  }
}

extern "C" void kernel_launch(void* const* d_in, const int* in_sizes, int n_in,
                              void* d_out, int out_size, void* d_ws, size_t ws_size,
                              hipStream_t stream)
{
  const float* x       = (const float*)d_in[0];
  const float* gate_W  = (const float*)d_in[1];
  const float* gate_b  = (const float*)d_in[2];
  const float* mag_W   = (const float*)d_in[3];
  const float* mag_b   = (const float*)d_in[4];
  const float* Wq      = (const float*)d_in[5];
  const float* Wk      = (const float*)d_in[6];
  const float* phase_W = (const float*)d_in[7];
  float* out = (float*)d_out;

  char* ws = (char*)d_ws;
  unsigned short* xbf = (unsigned short*)ws;                    // 32 MB @0 (reused as xg8)
  unsigned short* wbf = (unsigned short*)(ws + 33554432);       //  4 MB @32M: [gate;mag] bf16
  unsigned char*  wf8 = (unsigned char*)(ws + 37748736);        //  3 MB @36M: [q;k;p] fp8 x32
  unsigned short* gate_pre = (unsigned short*)(ws + 41943040);  // 32 MB @40M (reused as q_pre)
  unsigned short* mag_pre  = (unsigned short*)(ws + 75497472);  // 32 MB @72M (reused as k_pre)
  unsigned short* p_pre    = (unsigned short*)(ws + 109051904); // 32 MB @104M
  unsigned short* q_pre = gate_pre;
  unsigned short* k_pre = mag_pre;

  dim3 b256(256);
  cvt_all<<<dim3(1024, 21), b256, 0, stream>>>(x, gate_W, mag_W, Wq, Wk, phase_W,
                                               xbf, wbf, wf8);

  // gate+mag fused bf16 GEMM (N=2048)
  gemm_bt<<<dim3(16, 128), b256, 0, stream>>>(xbf, wbf, gate_b, mag_b,
                                              gate_pre, mag_pre, nullptr, 0b011);

  unsigned char* xg8 = (unsigned char*)xbf;   // xbf no longer needed
  select_k<<<ROWS / 4, b256, 0, stream>>>(gate_pre, mag_pre, x, gate_W, gate_b, xg8);

  // q+k+phase MX-fp8 GEMM (N=3072), bf16 out, x(1/32)
  gemm8<<<dim3(24, 128), b256, 0, stream>>>(xg8, wf8, q_pre, k_pre, p_pre);

  epilogue_k<<<ROWS / 4, b256, 0, stream>>>(q_pre, k_pre, p_pre, out);
}